// Round 1
// baseline (2868.342 us; speedup 1.0000x reference)
//
#include <hip/hip_runtime.h>
#include <cstdint>
#include <cstddef>

#define NN 8000
#define NE 128000
#define NDv 40
#define EDv 10

__device__ __forceinline__ float rcp_fast(float x) { return __builtin_amdgcn_rcpf(x); }
__device__ __forceinline__ float sigm(float x) { return rcp_fast(1.f + __expf(-x)); }
__device__ __forceinline__ float ftanh(float x) {
    float e = __expf(2.f * x);
    return 1.f - 2.f * rcp_fast(e + 1.f);
}
__device__ __forceinline__ float wsum(float v) {
    for (int o = 32; o; o >>= 1) v += __shfl_down(v, o);
    return v;
}
__device__ __forceinline__ float wmax(float v) {
    for (int o = 32; o; o >>= 1) v = fmaxf(v, __shfl_down(v, o));
    return v;
}

// ---------------- message passing ----------------

// A[n,i] = Uw[i,0:40]·h[n], B[n,i] = Uw[i,40:80]·h[n]
__global__ __launch_bounds__(256) void node_proj_kernel(const float* __restrict__ h, const float* __restrict__ Uw,
                                                        float* __restrict__ A, float* __restrict__ B) {
    int t = blockIdx.x * 256 + threadIdx.x;   // exactly 8000*40
    int n = t / NDv, i = t % NDv;
    const float* wa = Uw + i * 90;
    const float* hr = h + n * NDv;
    float a = 0.f, b = 0.f;
#pragma unroll
    for (int k = 0; k < NDv; ++k) { float hv = hr[k]; a += wa[k] * hv; b += wa[40 + k] * hv; }
    A[t] = a; B[t] = b;
}

// msg[src,i] += A[src,i] + B[dst,i] + Ub[i] + Uw[i,80:90]·ef[e]
__global__ __launch_bounds__(256) void edge_gather_kernel(const int* __restrict__ ei, const float* __restrict__ ef,
                                                          const float* __restrict__ Uw, const float* __restrict__ Ub,
                                                          const float* __restrict__ A, const float* __restrict__ B,
                                                          float* __restrict__ msg) {
    int t = blockIdx.x * 256 + threadIdx.x;   // exactly 128000*40
    int e = t / NDv, i = t % NDv;
    int s = ei[e], d = ei[NE + e];
    const float* we = Uw + i * 90 + 80;
    const float* efr = ef + e * EDv;
    float acc = Ub[i] + A[s * NDv + i] + B[d * NDv + i];
#pragma unroll
    for (int k = 0; k < EDv; ++k) acc += we[k] * efr[k];
    atomicAdd(&msg[s * NDv + i], acc);
}

// h_out[n,i] = relu(Mw[i,0:40]·h[n] + Mw[i,40:80]·msg[n] + Mb[i])
__global__ __launch_bounds__(256) void node_update_kernel(const float* __restrict__ h, const float* __restrict__ msg,
                                                          const float* __restrict__ Mw, const float* __restrict__ Mb,
                                                          float* __restrict__ hout) {
    int t = blockIdx.x * 256 + threadIdx.x;   // exactly 8000*40
    int n = t / NDv, i = t % NDv;
    const float* w = Mw + i * 80;
    const float* hr = h + n * NDv;
    const float* mr = msg + n * NDv;
    float acc = Mb[i];
#pragma unroll
    for (int k = 0; k < NDv; ++k) acc += w[k] * hr[k];
#pragma unroll
    for (int k = 0; k < NDv; ++k) acc += w[40 + k] * mr[k];
    hout[t] = fmaxf(acc, 0.f);
}

// ---------------- set2set (pair, per-node LSTM h_d=40) ----------------

// gatesT[j, n] = bih[j]+bhh[j] + Wih[j,:80]·q[n] + Whh[j,:40]·hh[n]  (transposed store for coalesced reads)
__global__ __launch_bounds__(256) void s2s_gates_kernel(const float* __restrict__ q, const float* __restrict__ hh,
                                                        const float* __restrict__ Wih, const float* __restrict__ Whh,
                                                        const float* __restrict__ bih, const float* __restrict__ bhh,
                                                        float* __restrict__ gatesT) {
    int t = blockIdx.x * 256 + threadIdx.x;   // exactly 8000*20
    int n = t % NN;
    int jg = t / NN;                           // 0..19, j = jg*8..jg*8+7 (uniform per wave -> scalar weight loads)
    float qr[80];
#pragma unroll
    for (int k4 = 0; k4 < 20; ++k4) {
        float4 v = *reinterpret_cast<const float4*>(q + n * 80 + k4 * 4);
        qr[k4 * 4 + 0] = v.x; qr[k4 * 4 + 1] = v.y; qr[k4 * 4 + 2] = v.z; qr[k4 * 4 + 3] = v.w;
    }
    float hr[40];
#pragma unroll
    for (int k4 = 0; k4 < 10; ++k4) {
        float4 v = *reinterpret_cast<const float4*>(hh + n * 40 + k4 * 4);
        hr[k4 * 4 + 0] = v.x; hr[k4 * 4 + 1] = v.y; hr[k4 * 4 + 2] = v.z; hr[k4 * 4 + 3] = v.w;
    }
#pragma unroll
    for (int jj = 0; jj < 8; ++jj) {
        int j = jg * 8 + jj;
        const float* wi = Wih + j * 80;
        const float* wh = Whh + j * 40;
        float acc = bih[j] + bhh[j];
#pragma unroll
        for (int k = 0; k < 80; ++k) acc += wi[k] * qr[k];
#pragma unroll
        for (int k = 0; k < 40; ++k) acc += wh[k] * hr[k];
        gatesT[j * NN + n] = acc;
    }
}

// per-node: LSTM pointwise update + 2-element attention + q_star=[h,r]
__global__ __launch_bounds__(256) void s2s_update_kernel(const float* __restrict__ gatesT,
                                                         const float* __restrict__ h0, const float* __restrict__ ht,
                                                         float* __restrict__ hh, float* __restrict__ cc,
                                                         float* __restrict__ q) {
    int n = blockIdx.x * 256 + threadIdx.x;
    if (n >= NN) return;
    float hreg[40];
    float e0 = 0.f, e1 = 0.f;
#pragma unroll
    for (int i = 0; i < 40; ++i) {
        float gi = gatesT[i * NN + n];
        float gf = gatesT[(40 + i) * NN + n];
        float gg = gatesT[(80 + i) * NN + n];
        float go = gatesT[(120 + i) * NN + n];
        float cn = sigm(gf) * cc[n * 40 + i] + sigm(gi) * ftanh(gg);
        cc[n * 40 + i] = cn;
        float hn = sigm(go) * ftanh(cn);
        hreg[i] = hn;
        e0 += h0[n * 40 + i] * hn;
        e1 += ht[n * 40 + i] * hn;
    }
    float m = fmaxf(e0, e1);
    float p0 = __expf(e0 - m), p1 = __expf(e1 - m);
    float inv = rcp_fast(p0 + p1);
    float a0 = p0 * inv, a1 = p1 * inv;
#pragma unroll
    for (int i = 0; i < 40; ++i) {
        hh[n * 40 + i] = hreg[i];
        q[n * 80 + i] = hreg[i];
        q[n * 80 + 40 + i] = a0 * h0[n * 40 + i] + a1 * ht[n * 40 + i];
    }
}

// ---------------- interaction GEMM: I = gu @ gv^T  (M=N=8000, K=80) ----------------

__global__ __launch_bounds__(256) void inter_kernel(const float* __restrict__ gu, const float* __restrict__ gv,
                                                    float* __restrict__ out) {
    __shared__ float sa[80][68];   // gu tile transposed [k][m], padded to 68 for bank spread + float4 align
    __shared__ float sb[80][68];   // gv tile transposed [k][n]
    int m0 = blockIdx.y * 64, n0 = blockIdx.x * 64;
    int tid = threadIdx.x;
#pragma unroll
    for (int it = 0; it < 5; ++it) {
        int idx4 = (tid + it * 256) * 4;
        int m = idx4 / 80, k = idx4 % 80;
        float4 va = *reinterpret_cast<const float4*>(gu + m0 * 80 + idx4);
        sa[k + 0][m] = va.x; sa[k + 1][m] = va.y; sa[k + 2][m] = va.z; sa[k + 3][m] = va.w;
        float4 vb = *reinterpret_cast<const float4*>(gv + n0 * 80 + idx4);
        sb[k + 0][m] = vb.x; sb[k + 1][m] = vb.y; sb[k + 2][m] = vb.z; sb[k + 3][m] = vb.w;
    }
    __syncthreads();
    int tx = tid & 15, ty = tid >> 4;
    float acc[4][4] = {};
#pragma unroll 8
    for (int k = 0; k < 80; ++k) {
        float4 a = *reinterpret_cast<const float4*>(&sa[k][ty * 4]);
        float4 b = *reinterpret_cast<const float4*>(&sb[k][tx * 4]);
        acc[0][0] += a.x * b.x; acc[0][1] += a.x * b.y; acc[0][2] += a.x * b.z; acc[0][3] += a.x * b.w;
        acc[1][0] += a.y * b.x; acc[1][1] += a.y * b.y; acc[1][2] += a.y * b.z; acc[1][3] += a.y * b.w;
        acc[2][0] += a.z * b.x; acc[2][1] += a.z * b.y; acc[2][2] += a.z * b.z; acc[2][3] += a.z * b.w;
        acc[3][0] += a.w * b.x; acc[3][1] += a.w * b.y; acc[3][2] += a.w * b.z; acc[3][3] += a.w * b.w;
    }
#pragma unroll
    for (int i = 0; i < 4; ++i)
#pragma unroll
        for (int j = 0; j < 4; ++j)
            out[(size_t)(m0 + ty * 4 + i) * NN + (n0 + tx * 4 + j)] = acc[i][j];
}

// ---------------- u_after = tanh(I) @ gv   (K-split over 5, atomic accumulate) ----------------

__global__ __launch_bounds__(256) void c2_kernel(const float* __restrict__ inter, const float* __restrict__ gvv,
                                                 float* __restrict__ uafter) {
    __shared__ float St[64][68];   // tanh(I) tile [row][k]
    __shared__ float Bc[64][80];   // gv chunk [k][f]
    int m0 = blockIdx.x * 64;
    int kbase = blockIdx.y * 1600;
    int tid = threadIdx.x;
    int rg = tid >> 3, cg = tid & 7;   // rows {2rg,2rg+1}, cols cg*10..+9
    float acc[2][10] = {};
    for (int kc = 0; kc < 25; ++kc) {
        int k0 = kbase + kc * 64;
        __syncthreads();
#pragma unroll
        for (int it = 0; it < 16; ++it) {
            int idx = tid + it * 256;
            int r = idx >> 6, kk = idx & 63;
            St[r][kk] = ftanh(inter[(size_t)(m0 + r) * NN + (k0 + kk)]);
        }
#pragma unroll
        for (int it = 0; it < 20; ++it) {
            int idx = tid + it * 256;
            Bc[idx / 80][idx % 80] = gvv[(size_t)k0 * 80 + idx];
        }
        __syncthreads();
#pragma unroll 4
        for (int kk = 0; kk < 64; ++kk) {
            float a0 = St[rg * 2 + 0][kk];
            float a1 = St[rg * 2 + 1][kk];
#pragma unroll
            for (int jj = 0; jj < 10; ++jj) {
                float b = Bc[kk][cg * 10 + jj];
                acc[0][jj] += a0 * b;
                acc[1][jj] += a1 * b;
            }
        }
    }
#pragma unroll
    for (int i = 0; i < 2; ++i)
#pragma unroll
        for (int jj = 0; jj < 10; ++jj)
            atomicAdd(&uafter[(m0 + rg * 2 + i) * 80 + cg * 10 + jj], acc[i][jj]);
}

// ---------------- v_after = tanh(I)^T @ gu ----------------

__global__ __launch_bounds__(256) void c3_kernel(const float* __restrict__ inter, const float* __restrict__ guu,
                                                 float* __restrict__ vafter) {
    __shared__ float St[64][68];   // tanh(I) tile [m(kk)][n(col)]
    __shared__ float Bc[64][80];   // gu chunk [m(kk)][f]
    int n0 = blockIdx.x * 64;
    int kbase = blockIdx.y * 1600;
    int tid = threadIdx.x;
    int rg = tid >> 3, cg = tid & 7;
    float acc[2][10] = {};
    for (int kc = 0; kc < 25; ++kc) {
        int k0 = kbase + kc * 64;
        __syncthreads();
#pragma unroll
        for (int it = 0; it < 16; ++it) {
            int idx = tid + it * 256;
            int kk = idx >> 6, c = idx & 63;
            St[kk][c] = ftanh(inter[(size_t)(k0 + kk) * NN + (n0 + c)]);
        }
#pragma unroll
        for (int it = 0; it < 20; ++it) {
            int idx = tid + it * 256;
            Bc[idx / 80][idx % 80] = guu[(size_t)k0 * 80 + idx];
        }
        __syncthreads();
#pragma unroll 4
        for (int kk = 0; kk < 64; ++kk) {
            float a0 = St[kk][rg * 2 + 0];
            float a1 = St[kk][rg * 2 + 1];
#pragma unroll
            for (int jj = 0; jj < 10; ++jj) {
                float b = Bc[kk][cg * 10 + jj];
                acc[0][jj] += a0 * b;
                acc[1][jj] += a1 * b;
            }
        }
    }
#pragma unroll
    for (int i = 0; i < 2; ++i)
#pragma unroll
        for (int jj = 0; jj < 10; ++jj)
            atomicAdd(&vafter[(n0 + rg * 2 + i) * 80 + cg * 10 + jj], acc[i][jj]);
}

// ---------------- set2set pool (batch 1, h_d=160) ----------------

__global__ __launch_bounds__(640) void pool_lstm_kernel(const float* __restrict__ Wih, const float* __restrict__ Whh,
                                                        const float* __restrict__ bih, const float* __restrict__ bhh,
                                                        float* __restrict__ q, float* __restrict__ h, float* __restrict__ c) {
    __shared__ float qs[320], hs[160], gts[640];
    int tid = threadIdx.x;
    if (tid < 320) qs[tid] = q[tid];
    if (tid < 160) hs[tid] = h[tid];
    __syncthreads();
    int wave = tid >> 6, lane = tid & 63;
    for (int j = wave; j < 640; j += 10) {
        const float* wi = Wih + j * 320;
        const float* wh = Whh + j * 160;
        float p = 0.f;
        for (int k = lane; k < 320; k += 64) p += wi[k] * qs[k];
        for (int k = lane; k < 160; k += 64) p += wh[k] * hs[k];
        p = wsum(p);
        if (lane == 0) gts[j] = p + bih[j] + bhh[j];
    }
    __syncthreads();
    if (tid < 160) {
        float cn = sigm(gts[160 + tid]) * c[tid] + sigm(gts[tid]) * ftanh(gts[320 + tid]);
        c[tid] = cn;
        float hn = sigm(gts[480 + tid]) * ftanh(cn);
        h[tid] = hn;
        q[tid] = hn;   // q_star[0:160] = h
    }
}

__global__ __launch_bounds__(256) void pool_scores_kernel(const float* __restrict__ after, const float* __restrict__ g,
                                                          const float* __restrict__ h, float* __restrict__ scores,
                                                          float* __restrict__ pmax) {
    int tid = threadIdx.x;
    int n = blockIdx.x * 256 + tid;
    float s = -3.4e38f;
    if (n < NN) {
        const float* ar = after + n * 80;
        const float* gr = g + n * 80;
        float acc = 0.f;
#pragma unroll 8
        for (int k = 0; k < 80; ++k) acc += ar[k] * h[k];
#pragma unroll 8
        for (int k = 0; k < 80; ++k) acc += gr[k] * h[80 + k];
        scores[n] = acc;
        s = acc;
    }
    __shared__ float red[4];
    float m = wmax(s);
    if ((tid & 63) == 0) red[tid >> 6] = m;
    __syncthreads();
    if (tid == 0) pmax[blockIdx.x] = fmaxf(fmaxf(red[0], red[1]), fmaxf(red[2], red[3]));
}

__global__ __launch_bounds__(256) void pool_softmax_kernel(float* __restrict__ scores, const float* __restrict__ pmax,
                                                           float* __restrict__ denom) {
    int tid = threadIdx.x;
    __shared__ float sm;
    __shared__ float red[4];
    float m = (tid < 32) ? pmax[tid] : -3.4e38f;
    m = wmax(m);
    if (tid == 0) sm = m;
    __syncthreads();
    float mm = sm;
    float lsum = 0.f;
    for (int n = tid; n < NN; n += 256) {
        float e = __expf(scores[n] - mm);
        scores[n] = e;
        lsum += e;
    }
    float w = wsum(lsum);
    if ((tid & 63) == 0) red[tid >> 6] = w;
    __syncthreads();
    if (tid == 0) denom[0] = red[0] + red[1] + red[2] + red[3];
}

__global__ __launch_bounds__(256) void pool_r_kernel(const float* __restrict__ after, const float* __restrict__ g,
                                                     const float* __restrict__ scores, const float* __restrict__ denom,
                                                     float* __restrict__ q) {
    int f = blockIdx.x;   // 0..159
    int tid = threadIdx.x;
    const float* x = (f < 80) ? (after + f) : (g + (f - 80));
    float acc = 0.f;
    for (int n = tid; n < NN; n += 256) acc += scores[n] * x[(size_t)n * 80];
    float w = wsum(acc);
    __shared__ float red[4];
    if ((tid & 63) == 0) red[tid >> 6] = w;
    __syncthreads();
    if (tid == 0) q[160 + f] = (red[0] + red[1] + red[2] + red[3]) * rcp_fast(denom[0]);
}

// ---------------- final MLP ----------------

__global__ __launch_bounds__(512) void mlp_kernel(const float* __restrict__ cu, const float* __restrict__ cv,
                                                  const float* __restrict__ w1, const float* __restrict__ b1,
                                                  const float* __restrict__ w2, const float* __restrict__ b2,
                                                  const float* __restrict__ w3, const float* __restrict__ b3,
                                                  const float* __restrict__ w4, const float* __restrict__ b4,
                                                  float* __restrict__ out) {
    __shared__ float x0[640], x1[360], x2[200], x3[120];
    int tid = threadIdx.x;
    if (tid < 320) x0[tid] = cu[tid];
    else if (tid < 640) x0[tid] = cv[tid - 320];
    __syncthreads();
    int wave = tid >> 6, lane = tid & 63;
    for (int j = wave; j < 360; j += 8) {
        const float* w = w1 + j * 640;
        float p = 0.f;
        for (int k = lane; k < 640; k += 64) p += w[k] * x0[k];
        p = wsum(p);
        if (lane == 0) x1[j] = fmaxf(p + b1[j], 0.f);
    }
    __syncthreads();
    for (int j = wave; j < 200; j += 8) {
        const float* w = w2 + j * 360;
        float p = 0.f;
        for (int k = lane; k < 360; k += 64) p += w[k] * x1[k];
        p = wsum(p);
        if (lane == 0) x2[j] = fmaxf(p + b2[j], 0.f);
    }
    __syncthreads();
    for (int j = wave; j < 120; j += 8) {
        const float* w = w3 + j * 200;
        float p = 0.f;
        for (int k = lane; k < 200; k += 64) p += w[k] * x2[k];
        p = wsum(p);
        if (lane == 0) x3[j] = fmaxf(p + b3[j], 0.f);
    }
    __syncthreads();
    if (wave == 0) {
        float p = 0.f;
        for (int k = lane; k < 120; k += 64) p += w4[k] * x3[k];
        p = wsum(p);
        if (lane == 0) out[0] = p + b4[0];
    }
}

// ---------------- launch ----------------

extern "C" void kernel_launch(void* const* d_in, const int* in_sizes, int n_in,
                              void* d_out, int out_size, void* d_ws, size_t ws_size,
                              hipStream_t stream) {
    const float* nodes_u = (const float*)d_in[0];
    const int* ei_u = (const int*)d_in[1];
    const float* ef_u = (const float*)d_in[2];
    const float* nodes_v = (const float*)d_in[3];
    const int* ei_v = (const int*)d_in[4];
    const float* ef_v = (const float*)d_in[5];
    const float* Uw_u = (const float*)d_in[6];
    const float* Ub_u = (const float*)d_in[7];
    const float* Mw_u = (const float*)d_in[8];
    const float* Mb_u = (const float*)d_in[9];
    const float* Uw_v = (const float*)d_in[10];
    const float* Ub_v = (const float*)d_in[11];
    const float* Mw_v = (const float*)d_in[12];
    const float* Mb_v = (const float*)d_in[13];
    const float* lsWih = (const float*)d_in[14];
    const float* lsWhh = (const float*)d_in[15];
    const float* lsbih = (const float*)d_in[16];
    const float* lsbhh = (const float*)d_in[17];
    const float* lvWih = (const float*)d_in[18];
    const float* lvWhh = (const float*)d_in[19];
    const float* lvbih = (const float*)d_in[20];
    const float* lvbhh = (const float*)d_in[21];
    const float* gsWih = (const float*)d_in[22];
    const float* gsWhh = (const float*)d_in[23];
    const float* gsbih = (const float*)d_in[24];
    const float* gsbhh = (const float*)d_in[25];
    const float* gvWih = (const float*)d_in[26];
    const float* gvWhh = (const float*)d_in[27];
    const float* gvbih = (const float*)d_in[28];
    const float* gvbhh = (const float*)d_in[29];
    const float* w1 = (const float*)d_in[30];
    const float* b1 = (const float*)d_in[31];
    const float* w2 = (const float*)d_in[32];
    const float* b2 = (const float*)d_in[33];
    const float* w3 = (const float*)d_in[34];
    const float* b3 = (const float*)d_in[35];
    const float* w4 = (const float*)d_in[36];
    const float* b4 = (const float*)d_in[37];

    float* ws = (float*)d_ws;
    float* hA_u = ws + 0;
    float* hB_u = ws + 320000;
    float* hA_v = ws + 640000;
    float* hB_v = ws + 960000;
    float* msg  = ws + 1280000;
    float* Apro = ws + 1600000;
    float* Bpro = ws + 1920000;
    float* q_u  = ws + 2240000;   // gu [8000,80]
    float* q_v  = ws + 2880000;   // gv [8000,80]
    float* hh   = ws + 3520000;
    float* cc   = ws + 3840000;
    float* gT   = ws + 4160000;   // gates transposed [160][8000]
    float* uaf  = ws + 5440000;
    float* vaf  = ws + 6080000;
    float* scores = ws + 6720000;
    float* pmax = ws + 6728000;
    float* pden = ws + 6728032;
    float* pq_u = ws + 6728040;
    float* ph_u = ws + 6728360;
    float* pc_u = ws + 6728520;
    float* pq_v = ws + 6728680;
    float* ph_v = ws + 6729000;
    float* pc_v = ws + 6729160;

    float* out = (float*)d_out;
    float* inter = out + 1;

    // ---- message passing: u ----
    {
        const float* cur = nodes_u;
        float* nxt[3] = {hA_u, hB_u, hA_u};
        for (int k = 0; k < 3; ++k) {
            node_proj_kernel<<<1250, 256, 0, stream>>>(cur, Uw_u + k * 3600, Apro, Bpro);
            hipMemsetAsync(msg, 0, 320000 * sizeof(float), stream);
            edge_gather_kernel<<<20000, 256, 0, stream>>>(ei_u, ef_u, Uw_u + k * 3600, Ub_u + k * 40, Apro, Bpro, msg);
            node_update_kernel<<<1250, 256, 0, stream>>>(cur, msg, Mw_u + k * 3200, Mb_u + k * 40, nxt[k]);
            cur = nxt[k];
        }
    }
    // ---- message passing: v ----
    {
        const float* cur = nodes_v;
        float* nxt[3] = {hA_v, hB_v, hA_v};
        for (int k = 0; k < 3; ++k) {
            node_proj_kernel<<<1250, 256, 0, stream>>>(cur, Uw_v + k * 3600, Apro, Bpro);
            hipMemsetAsync(msg, 0, 320000 * sizeof(float), stream);
            edge_gather_kernel<<<20000, 256, 0, stream>>>(ei_v, ef_v, Uw_v + k * 3600, Ub_v + k * 40, Apro, Bpro, msg);
            node_update_kernel<<<1250, 256, 0, stream>>>(cur, msg, Mw_v + k * 3200, Mb_v + k * 40, nxt[k]);
            cur = nxt[k];
        }
    }

    // ---- set2set pair: u (gu = q_u), v (gv = q_v) ----
    hipMemsetAsync(q_u, 0, 640000 * sizeof(float), stream);
    hipMemsetAsync(hh, 0, 640000 * sizeof(float), stream);   // hh + cc contiguous
    for (int stp = 0; stp < 2; ++stp) {
        s2s_gates_kernel<<<625, 256, 0, stream>>>(q_u, hh, lsWih, lsWhh, lsbih, lsbhh, gT);
        s2s_update_kernel<<<32, 256, 0, stream>>>(gT, nodes_u, hA_u, hh, cc, q_u);
    }
    hipMemsetAsync(q_v, 0, 640000 * sizeof(float), stream);
    hipMemsetAsync(hh, 0, 640000 * sizeof(float), stream);
    for (int stp = 0; stp < 2; ++stp) {
        s2s_gates_kernel<<<625, 256, 0, stream>>>(q_v, hh, lvWih, lvWhh, lvbih, lvbhh, gT);
        s2s_update_kernel<<<32, 256, 0, stream>>>(gT, nodes_v, hA_v, hh, cc, q_v);
    }

    // ---- interaction + after-features ----
    inter_kernel<<<dim3(125, 125), 256, 0, stream>>>(q_u, q_v, inter);
    hipMemsetAsync(uaf, 0, 1280000 * sizeof(float), stream);   // uaf + vaf contiguous
    c2_kernel<<<dim3(125, 5), 256, 0, stream>>>(inter, q_v, uaf);
    c3_kernel<<<dim3(125, 5), 256, 0, stream>>>(inter, q_u, vaf);

    // ---- pools ----
    hipMemsetAsync(pq_u, 0, 640 * sizeof(float), stream);   // pq+ph+pc contiguous
    for (int stp = 0; stp < 2; ++stp) {
        pool_lstm_kernel<<<1, 640, 0, stream>>>(gsWih, gsWhh, gsbih, gsbhh, pq_u, ph_u, pc_u);
        pool_scores_kernel<<<32, 256, 0, stream>>>(uaf, q_u, ph_u, scores, pmax);
        pool_softmax_kernel<<<1, 256, 0, stream>>>(scores, pmax, pden);
        pool_r_kernel<<<160, 256, 0, stream>>>(uaf, q_u, scores, pden, pq_u);
    }
    hipMemsetAsync(pq_v, 0, 640 * sizeof(float), stream);
    for (int stp = 0; stp < 2; ++stp) {
        pool_lstm_kernel<<<1, 640, 0, stream>>>(gvWih, gvWhh, gvbih, gvbhh, pq_v, ph_v, pc_v);
        pool_scores_kernel<<<32, 256, 0, stream>>>(vaf, q_v, ph_v, scores, pmax);
        pool_softmax_kernel<<<1, 256, 0, stream>>>(scores, pmax, pden);
        pool_r_kernel<<<160, 256, 0, stream>>>(vaf, q_v, scores, pden, pq_v);
    }

    // ---- final MLP ----
    mlp_kernel<<<1, 512, 0, stream>>>(pq_u, pq_v, w1, b1, w2, b2, w3, b3, w4, b4, out);
}

// Round 2
// 2229.484 us; speedup vs baseline: 1.2865x; 1.2865x over previous
//
#include <hip/hip_runtime.h>
#include <cstdint>
#include <cstddef>

#define NN 8000
#define NE 128000
#define NDv 40
#define EDv 10

typedef __attribute__((ext_vector_type(8))) short short8v;
typedef __attribute__((ext_vector_type(4))) float f32x4;

__device__ __forceinline__ float rcp_fast(float x) { return __builtin_amdgcn_rcpf(x); }
__device__ __forceinline__ float sigm(float x) { return rcp_fast(1.f + __expf(-x)); }
__device__ __forceinline__ float ftanh(float x) {
    float e = __expf(2.f * x);
    return 1.f - 2.f * rcp_fast(e + 1.f);
}
__device__ __forceinline__ short f2bf(float x) {   // RNE f32 -> bf16
    unsigned u = __builtin_bit_cast(unsigned, x);
    u += 0x7fffu + ((u >> 16) & 1u);
    return (short)(u >> 16);
}
__device__ __forceinline__ float wsum(float v) {
    for (int o = 32; o; o >>= 1) v += __shfl_down(v, o);
    return v;
}
__device__ __forceinline__ float wmax(float v) {
    for (int o = 32; o; o >>= 1) v = fmaxf(v, __shfl_down(v, o));
    return v;
}

// ---------------- message passing ----------------

__global__ __launch_bounds__(256) void node_proj_kernel(const float* __restrict__ h, const float* __restrict__ Uw,
                                                        float* __restrict__ A, float* __restrict__ B) {
    int t = blockIdx.x * 256 + threadIdx.x;   // exactly 8000*40
    int n = t / NDv, i = t % NDv;
    const float* wa = Uw + i * 90;
    const float* hr = h + n * NDv;
    float a = 0.f, b = 0.f;
#pragma unroll
    for (int k = 0; k < NDv; ++k) { float hv = hr[k]; a += wa[k] * hv; b += wa[40 + k] * hv; }
    A[t] = a; B[t] = b;
}

__global__ __launch_bounds__(256) void edge_gather_kernel(const int* __restrict__ ei, const float* __restrict__ ef,
                                                          const float* __restrict__ Uw, const float* __restrict__ Ub,
                                                          const float* __restrict__ A, const float* __restrict__ B,
                                                          float* __restrict__ msg) {
    int t = blockIdx.x * 256 + threadIdx.x;   // exactly 128000*40
    int e = t / NDv, i = t % NDv;
    int s = ei[e], d = ei[NE + e];
    const float* we = Uw + i * 90 + 80;
    const float* efr = ef + e * EDv;
    float acc = Ub[i] + A[s * NDv + i] + B[d * NDv + i];
#pragma unroll
    for (int k = 0; k < EDv; ++k) acc += we[k] * efr[k];
    atomicAdd(&msg[s * NDv + i], acc);
}

__global__ __launch_bounds__(256) void node_update_kernel(const float* __restrict__ h, const float* __restrict__ msg,
                                                          const float* __restrict__ Mw, const float* __restrict__ Mb,
                                                          float* __restrict__ hout) {
    int t = blockIdx.x * 256 + threadIdx.x;   // exactly 8000*40
    int n = t / NDv, i = t % NDv;
    const float* w = Mw + i * 80;
    const float* hr = h + n * NDv;
    const float* mr = msg + n * NDv;
    float acc = Mb[i];
#pragma unroll
    for (int k = 0; k < NDv; ++k) acc += w[k] * hr[k];
#pragma unroll
    for (int k = 0; k < NDv; ++k) acc += w[40 + k] * mr[k];
    hout[t] = fmaxf(acc, 0.f);
}

// ---------------- set2set (pair, per-node LSTM h_d=40) ----------------

__global__ __launch_bounds__(256) void s2s_gates_kernel(const float* __restrict__ q, const float* __restrict__ hh,
                                                        const float* __restrict__ Wih, const float* __restrict__ Whh,
                                                        const float* __restrict__ bih, const float* __restrict__ bhh,
                                                        float* __restrict__ gatesT) {
    int t = blockIdx.x * 256 + threadIdx.x;   // exactly 8000*20
    int n = t % NN;
    int jg = t / NN;
    float qr[80];
#pragma unroll
    for (int k4 = 0; k4 < 20; ++k4) {
        float4 v = *reinterpret_cast<const float4*>(q + n * 80 + k4 * 4);
        qr[k4 * 4 + 0] = v.x; qr[k4 * 4 + 1] = v.y; qr[k4 * 4 + 2] = v.z; qr[k4 * 4 + 3] = v.w;
    }
    float hr[40];
#pragma unroll
    for (int k4 = 0; k4 < 10; ++k4) {
        float4 v = *reinterpret_cast<const float4*>(hh + n * 40 + k4 * 4);
        hr[k4 * 4 + 0] = v.x; hr[k4 * 4 + 1] = v.y; hr[k4 * 4 + 2] = v.z; hr[k4 * 4 + 3] = v.w;
    }
#pragma unroll
    for (int jj = 0; jj < 8; ++jj) {
        int j = jg * 8 + jj;
        const float* wi = Wih + j * 80;
        const float* wh = Whh + j * 40;
        float acc = bih[j] + bhh[j];
#pragma unroll
        for (int k = 0; k < 80; ++k) acc += wi[k] * qr[k];
#pragma unroll
        for (int k = 0; k < 40; ++k) acc += wh[k] * hr[k];
        gatesT[j * NN + n] = acc;
    }
}

__global__ __launch_bounds__(256) void s2s_update_kernel(const float* __restrict__ gatesT,
                                                         const float* __restrict__ h0, const float* __restrict__ ht,
                                                         float* __restrict__ hh, float* __restrict__ cc,
                                                         float* __restrict__ q) {
    int n = blockIdx.x * 256 + threadIdx.x;
    if (n >= NN) return;
    float hreg[40];
    float e0 = 0.f, e1 = 0.f;
#pragma unroll
    for (int i = 0; i < 40; ++i) {
        float gi = gatesT[i * NN + n];
        float gf = gatesT[(40 + i) * NN + n];
        float gg = gatesT[(80 + i) * NN + n];
        float go = gatesT[(120 + i) * NN + n];
        float cn = sigm(gf) * cc[n * 40 + i] + sigm(gi) * ftanh(gg);
        cc[n * 40 + i] = cn;
        float hn = sigm(go) * ftanh(cn);
        hreg[i] = hn;
        e0 += h0[n * 40 + i] * hn;
        e1 += ht[n * 40 + i] * hn;
    }
    float m = fmaxf(e0, e1);
    float p0 = __expf(e0 - m), p1 = __expf(e1 - m);
    float inv = rcp_fast(p0 + p1);
    float a0 = p0 * inv, a1 = p1 * inv;
#pragma unroll
    for (int i = 0; i < 40; ++i) {
        hh[n * 40 + i] = hreg[i];
        q[n * 80 + i] = hreg[i];
        q[n * 80 + 40 + i] = a0 * h0[n * 40 + i] + a1 * ht[n * 40 + i];
    }
}

// ---------------- bf16 casts ----------------

// row-major padded [8000][96] bf16 (last 16 = 0)
__global__ __launch_bounds__(256) void cast_pad_kernel(const float* __restrict__ g, short* __restrict__ o) {
    int t = blockIdx.x * 256 + threadIdx.x;   // exactly 8000*96
    int m = t / 96, k = t % 96;
    o[t] = (k < 80) ? f2bf(g[m * 80 + k]) : (short)0;
}

// transposed [80][8000] bf16
__global__ __launch_bounds__(256) void cast_t_kernel(const float* __restrict__ g, short* __restrict__ o) {
    int t = blockIdx.x * 256 + threadIdx.x;   // exactly 80*8000
    int m = t % NN, f = t / NN;
    o[t] = f2bf(g[m * 80 + f]);
}

// ---------------- interaction: I = gu @ gv^T via MFMA ----------------
// block 64x64 tile, 4 waves, wave = 16-row strip; frags straight from L2.

__global__ __launch_bounds__(256) void inter_mfma_kernel(const short* __restrict__ gub, const short* __restrict__ gvb,
                                                         float* __restrict__ out) {
    int tid = threadIdx.x;
    int w = tid >> 6, l = tid & 63;
    int lrow = l & 15, lk = l >> 4;
    int m0 = blockIdx.y * 64, n0 = blockIdx.x * 64;
    const short* arow = gub + (size_t)(m0 + w * 16 + lrow) * 96 + lk * 8;
    f32x4 acc[4] = {};
#pragma unroll
    for (int ks = 0; ks < 3; ++ks) {
        short8v a = *reinterpret_cast<const short8v*>(arow + ks * 32);
#pragma unroll
        for (int nt = 0; nt < 4; ++nt) {
            short8v b = *reinterpret_cast<const short8v*>(gvb + (size_t)(n0 + nt * 16 + lrow) * 96 + ks * 32 + lk * 8);
            acc[nt] = __builtin_amdgcn_mfma_f32_16x16x32_bf16(a, b, acc[nt], 0, 0, 0);
        }
    }
#pragma unroll
    for (int nt = 0; nt < 4; ++nt)
#pragma unroll
        for (int r = 0; r < 4; ++r)
            out[(size_t)(m0 + w * 16 + lk * 4 + r) * NN + (n0 + nt * 16 + lrow)] = acc[nt][r];
}

// ---------------- u_afterT[f][m] = sum_n tanh(I[m][n]) * gv[n][f] ----------------
// grid (125 m-tiles, 5 n-splits); wave = 16-row strip; A-frag = tanh(I) from global.

__global__ __launch_bounds__(256) void after_u_kernel(const float* __restrict__ I, const short* __restrict__ gvT,
                                                      float* __restrict__ uafT) {
    int tid = threadIdx.x;
    int w = tid >> 6, l = tid & 63;
    int lrow = l & 15, lk = l >> 4;
    int m = blockIdx.x * 64 + w * 16 + lrow;
    int nbase = blockIdx.y * 1600;
    f32x4 acc[5] = {};
    for (int nc = 0; nc < 50; ++nc) {
        int n = nbase + nc * 32 + lk * 8;
        const float* ip = I + (size_t)m * NN + n;
        short8v a;
#pragma unroll
        for (int j = 0; j < 8; ++j) a[j] = f2bf(ftanh(ip[j]));
#pragma unroll
        for (int ft = 0; ft < 5; ++ft) {
            short8v b = *reinterpret_cast<const short8v*>(gvT + (ft * 16 + lrow) * NN + n);
            acc[ft] = __builtin_amdgcn_mfma_f32_16x16x32_bf16(a, b, acc[ft], 0, 0, 0);
        }
    }
    int mout = blockIdx.x * 64 + w * 16 + lk * 4;
#pragma unroll
    for (int ft = 0; ft < 5; ++ft)
#pragma unroll
        for (int r = 0; r < 4; ++r)
            atomicAdd(&uafT[(ft * 16 + lrow) * NN + mout + r], acc[ft][r]);
}

// ---------------- v_afterT[f][n] = sum_m gu[m][f] * tanh(I[m][n]) ----------------
// grid (125 n-tiles, 5 m-splits); P staged transposed in LDS; A = guT.

__global__ __launch_bounds__(256) void after_v_kernel(const float* __restrict__ I, const short* __restrict__ guT,
                                                      float* __restrict__ vafT) {
    __shared__ short PT[64][40];   // [n_local][m_local(32)+pad]
    int tid = threadIdx.x;
    int w = tid >> 6, l = tid & 63;
    int lcol = l & 15, lk = l >> 4;
    int n0 = blockIdx.x * 64;
    int mbase = blockIdx.y * 1600;
    int lr = tid & 31;            // load: m_local
    int lc = (tid >> 5) * 8;      // load: n_local base
    f32x4 acc[5] = {};
    for (int mc = 0; mc < 50; ++mc) {
        int mrow = mbase + mc * 32 + lr;
        const float* ip = I + (size_t)mrow * NN + n0 + lc;
        float v[8];
#pragma unroll
        for (int j = 0; j < 8; ++j) v[j] = ftanh(ip[j]);
        __syncthreads();
#pragma unroll
        for (int j = 0; j < 8; ++j) PT[lc + j][lr] = f2bf(v[j]);
        __syncthreads();
        short8v b = *reinterpret_cast<const short8v*>(&PT[w * 16 + lcol][lk * 8]);
#pragma unroll
        for (int ft = 0; ft < 5; ++ft) {
            short8v a = *reinterpret_cast<const short8v*>(guT + (ft * 16 + lcol) * NN + mbase + mc * 32 + lk * 8);
            acc[ft] = __builtin_amdgcn_mfma_f32_16x16x32_bf16(a, b, acc[ft], 0, 0, 0);
        }
    }
    int ncol = n0 + w * 16 + lcol;
#pragma unroll
    for (int ft = 0; ft < 5; ++ft)
#pragma unroll
        for (int r = 0; r < 4; ++r)
            atomicAdd(&vafT[(ft * 16 + lk * 4 + r) * NN + ncol], acc[ft][r]);
}

// ---------------- set2set pool (batch 1, h_d=160); after arrays are [80][8000] ----------------

__global__ __launch_bounds__(640) void pool_lstm_kernel(const float* __restrict__ Wih, const float* __restrict__ Whh,
                                                        const float* __restrict__ bih, const float* __restrict__ bhh,
                                                        float* __restrict__ q, float* __restrict__ h, float* __restrict__ c) {
    __shared__ float qs[320], hs[160], gts[640];
    int tid = threadIdx.x;
    if (tid < 320) qs[tid] = q[tid];
    if (tid < 160) hs[tid] = h[tid];
    __syncthreads();
    int wave = tid >> 6, lane = tid & 63;
    for (int j = wave; j < 640; j += 10) {
        const float* wi = Wih + j * 320;
        const float* wh = Whh + j * 160;
        float p = 0.f;
        for (int k = lane; k < 320; k += 64) p += wi[k] * qs[k];
        for (int k = lane; k < 160; k += 64) p += wh[k] * hs[k];
        p = wsum(p);
        if (lane == 0) gts[j] = p + bih[j] + bhh[j];
    }
    __syncthreads();
    if (tid < 160) {
        float cn = sigm(gts[160 + tid]) * c[tid] + sigm(gts[tid]) * ftanh(gts[320 + tid]);
        c[tid] = cn;
        float hn = sigm(gts[480 + tid]) * ftanh(cn);
        h[tid] = hn;
        q[tid] = hn;
    }
}

__global__ __launch_bounds__(256) void pool_scores_kernel(const float* __restrict__ afT, const float* __restrict__ g,
                                                          const float* __restrict__ h, float* __restrict__ scores,
                                                          float* __restrict__ pmax) {
    int tid = threadIdx.x;
    int n = blockIdx.x * 256 + tid;
    float s = -3.4e38f;
    if (n < NN) {
        float acc = 0.f;
#pragma unroll 8
        for (int k = 0; k < 80; ++k) acc += afT[k * NN + n] * h[k];
        const float* gr = g + n * 80;
#pragma unroll 8
        for (int k = 0; k < 80; ++k) acc += gr[k] * h[80 + k];
        scores[n] = acc;
        s = acc;
    }
    __shared__ float red[4];
    float m = wmax(s);
    if ((tid & 63) == 0) red[tid >> 6] = m;
    __syncthreads();
    if (tid == 0) pmax[blockIdx.x] = fmaxf(fmaxf(red[0], red[1]), fmaxf(red[2], red[3]));
}

__global__ __launch_bounds__(256) void pool_softmax_kernel(float* __restrict__ scores, const float* __restrict__ pmax,
                                                           float* __restrict__ denom) {
    int tid = threadIdx.x;
    __shared__ float sm;
    __shared__ float red[4];
    float m = (tid < 32) ? pmax[tid] : -3.4e38f;
    m = wmax(m);
    if (tid == 0) sm = m;
    __syncthreads();
    float mm = sm;
    float lsum = 0.f;
    for (int n = tid; n < NN; n += 256) {
        float e = __expf(scores[n] - mm);
        scores[n] = e;
        lsum += e;
    }
    float w = wsum(lsum);
    if ((tid & 63) == 0) red[tid >> 6] = w;
    __syncthreads();
    if (tid == 0) denom[0] = red[0] + red[1] + red[2] + red[3];
}

__global__ __launch_bounds__(256) void pool_r_kernel(const float* __restrict__ afT, const float* __restrict__ g,
                                                     const float* __restrict__ scores, const float* __restrict__ denom,
                                                     float* __restrict__ q) {
    int f = blockIdx.x;   // 0..159
    int tid = threadIdx.x;
    float acc = 0.f;
    if (f < 80) {
        const float* x = afT + (size_t)f * NN;
        for (int n = tid; n < NN; n += 256) acc += scores[n] * x[n];
    } else {
        const float* x = g + (f - 80);
        for (int n = tid; n < NN; n += 256) acc += scores[n] * x[(size_t)n * 80];
    }
    float w = wsum(acc);
    __shared__ float red[4];
    if ((tid & 63) == 0) red[tid >> 6] = w;
    __syncthreads();
    if (tid == 0) q[160 + f] = (red[0] + red[1] + red[2] + red[3]) * rcp_fast(denom[0]);
}

// ---------------- final MLP ----------------

__global__ __launch_bounds__(512) void mlp_kernel(const float* __restrict__ cu, const float* __restrict__ cv,
                                                  const float* __restrict__ w1, const float* __restrict__ b1,
                                                  const float* __restrict__ w2, const float* __restrict__ b2,
                                                  const float* __restrict__ w3, const float* __restrict__ b3,
                                                  const float* __restrict__ w4, const float* __restrict__ b4,
                                                  float* __restrict__ out) {
    __shared__ float x0[640], x1[360], x2[200], x3[120];
    int tid = threadIdx.x;
    if (tid < 320) x0[tid] = cu[tid];
    else if (tid < 640) x0[tid] = cv[tid - 320];
    __syncthreads();
    int wave = tid >> 6, lane = tid & 63;
    for (int j = wave; j < 360; j += 8) {
        const float* w = w1 + j * 640;
        float p = 0.f;
        for (int k = lane; k < 640; k += 64) p += w[k] * x0[k];
        p = wsum(p);
        if (lane == 0) x1[j] = fmaxf(p + b1[j], 0.f);
    }
    __syncthreads();
    for (int j = wave; j < 200; j += 8) {
        const float* w = w2 + j * 360;
        float p = 0.f;
        for (int k = lane; k < 360; k += 64) p += w[k] * x1[k];
        p = wsum(p);
        if (lane == 0) x2[j] = fmaxf(p + b2[j], 0.f);
    }
    __syncthreads();
    for (int j = wave; j < 120; j += 8) {
        const float* w = w3 + j * 200;
        float p = 0.f;
        for (int k = lane; k < 200; k += 64) p += w[k] * x2[k];
        p = wsum(p);
        if (lane == 0) x3[j] = fmaxf(p + b3[j], 0.f);
    }
    __syncthreads();
    if (wave == 0) {
        float p = 0.f;
        for (int k = lane; k < 120; k += 64) p += w4[k] * x3[k];
        p = wsum(p);
        if (lane == 0) out[0] = p + b4[0];
    }
}

// ---------------- launch ----------------

extern "C" void kernel_launch(void* const* d_in, const int* in_sizes, int n_in,
                              void* d_out, int out_size, void* d_ws, size_t ws_size,
                              hipStream_t stream) {
    const float* nodes_u = (const float*)d_in[0];
    const int* ei_u = (const int*)d_in[1];
    const float* ef_u = (const float*)d_in[2];
    const float* nodes_v = (const float*)d_in[3];
    const int* ei_v = (const int*)d_in[4];
    const float* ef_v = (const float*)d_in[5];
    const float* Uw_u = (const float*)d_in[6];
    const float* Ub_u = (const float*)d_in[7];
    const float* Mw_u = (const float*)d_in[8];
    const float* Mb_u = (const float*)d_in[9];
    const float* Uw_v = (const float*)d_in[10];
    const float* Ub_v = (const float*)d_in[11];
    const float* Mw_v = (const float*)d_in[12];
    const float* Mb_v = (const float*)d_in[13];
    const float* lsWih = (const float*)d_in[14];
    const float* lsWhh = (const float*)d_in[15];
    const float* lsbih = (const float*)d_in[16];
    const float* lsbhh = (const float*)d_in[17];
    const float* lvWih = (const float*)d_in[18];
    const float* lvWhh = (const float*)d_in[19];
    const float* lvbih = (const float*)d_in[20];
    const float* lvbhh = (const float*)d_in[21];
    const float* gsWih = (const float*)d_in[22];
    const float* gsWhh = (const float*)d_in[23];
    const float* gsbih = (const float*)d_in[24];
    const float* gsbhh = (const float*)d_in[25];
    const float* gvWih = (const float*)d_in[26];
    const float* gvWhh = (const float*)d_in[27];
    const float* gvbih = (const float*)d_in[28];
    const float* gvbhh = (const float*)d_in[29];
    const float* w1 = (const float*)d_in[30];
    const float* b1 = (const float*)d_in[31];
    const float* w2 = (const float*)d_in[32];
    const float* b2 = (const float*)d_in[33];
    const float* w3 = (const float*)d_in[34];
    const float* b3 = (const float*)d_in[35];
    const float* w4 = (const float*)d_in[36];
    const float* b4 = (const float*)d_in[37];

    float* ws = (float*)d_ws;
    float* hA_u = ws + 0;
    float* hB_u = ws + 320000;
    float* hA_v = ws + 640000;
    float* hB_v = ws + 960000;
    float* msg  = ws + 1280000;
    float* Apro = ws + 1600000;
    float* Bpro = ws + 1920000;
    float* q_u  = ws + 2240000;   // gu [8000,80]
    float* q_v  = ws + 2880000;   // gv [8000,80]
    float* hh   = ws + 3520000;
    float* cc   = ws + 3840000;
    float* gT   = ws + 4160000;   // gates transposed [160][8000]
    float* uafT = ws + 5440000;   // [80][8000]
    float* vafT = ws + 6080000;   // [80][8000]
    float* scores = ws + 6720000;
    float* pmax = ws + 6728000;
    float* pden = ws + 6728032;
    float* pq_u = ws + 6728040;
    float* ph_u = ws + 6728360;
    float* pc_u = ws + 6728520;
    float* pq_v = ws + 6728680;
    float* ph_v = ws + 6729000;
    float* pc_v = ws + 6729160;

    // bf16 buffers reuse the (dead by then) message-passing region
    short* guT = (short*)(ws + 0);        // [80][8000]
    short* gvT = (short*)(ws + 320000);   // [80][8000]
    short* gub = (short*)(ws + 640000);   // [8000][96]
    short* gvb = (short*)(ws + 1024000);  // [8000][96]

    float* out = (float*)d_out;
    float* inter = out + 1;

    // ---- message passing: u ----
    {
        const float* cur = nodes_u;
        float* nxt[3] = {hA_u, hB_u, hA_u};
        for (int k = 0; k < 3; ++k) {
            node_proj_kernel<<<1250, 256, 0, stream>>>(cur, Uw_u + k * 3600, Apro, Bpro);
            hipMemsetAsync(msg, 0, 320000 * sizeof(float), stream);
            edge_gather_kernel<<<20000, 256, 0, stream>>>(ei_u, ef_u, Uw_u + k * 3600, Ub_u + k * 40, Apro, Bpro, msg);
            node_update_kernel<<<1250, 256, 0, stream>>>(cur, msg, Mw_u + k * 3200, Mb_u + k * 40, nxt[k]);
            cur = nxt[k];
        }
    }
    // ---- message passing: v ----
    {
        const float* cur = nodes_v;
        float* nxt[3] = {hA_v, hB_v, hA_v};
        for (int k = 0; k < 3; ++k) {
            node_proj_kernel<<<1250, 256, 0, stream>>>(cur, Uw_v + k * 3600, Apro, Bpro);
            hipMemsetAsync(msg, 0, 320000 * sizeof(float), stream);
            edge_gather_kernel<<<20000, 256, 0, stream>>>(ei_v, ef_v, Uw_v + k * 3600, Ub_v + k * 40, Apro, Bpro, msg);
            node_update_kernel<<<1250, 256, 0, stream>>>(cur, msg, Mw_v + k * 3200, Mb_v + k * 40, nxt[k]);
            cur = nxt[k];
        }
    }

    // ---- set2set pair: u (gu = q_u), v (gv = q_v) ----
    hipMemsetAsync(q_u, 0, 640000 * sizeof(float), stream);
    hipMemsetAsync(hh, 0, 640000 * sizeof(float), stream);   // hh + cc contiguous
    for (int stp = 0; stp < 2; ++stp) {
        s2s_gates_kernel<<<625, 256, 0, stream>>>(q_u, hh, lsWih, lsWhh, lsbih, lsbhh, gT);
        s2s_update_kernel<<<32, 256, 0, stream>>>(gT, nodes_u, hA_u, hh, cc, q_u);
    }
    hipMemsetAsync(q_v, 0, 640000 * sizeof(float), stream);
    hipMemsetAsync(hh, 0, 640000 * sizeof(float), stream);
    for (int stp = 0; stp < 2; ++stp) {
        s2s_gates_kernel<<<625, 256, 0, stream>>>(q_v, hh, lvWih, lvWhh, lvbih, lvbhh, gT);
        s2s_update_kernel<<<32, 256, 0, stream>>>(gT, nodes_v, hA_v, hh, cc, q_v);
    }

    // ---- bf16 casts (msg-passing buffers are dead now) ----
    cast_t_kernel<<<2500, 256, 0, stream>>>(q_u, guT);
    cast_t_kernel<<<2500, 256, 0, stream>>>(q_v, gvT);
    cast_pad_kernel<<<3000, 256, 0, stream>>>(q_u, gub);
    cast_pad_kernel<<<3000, 256, 0, stream>>>(q_v, gvb);

    // ---- interaction + after-features (MFMA) ----
    inter_mfma_kernel<<<dim3(125, 125), 256, 0, stream>>>(gub, gvb, inter);
    hipMemsetAsync(uafT, 0, 1280000 * sizeof(float), stream);   // uafT + vafT contiguous
    after_u_kernel<<<dim3(125, 5), 256, 0, stream>>>(inter, gvT, uafT);
    after_v_kernel<<<dim3(125, 5), 256, 0, stream>>>(inter, guT, vafT);

    // ---- pools ----
    hipMemsetAsync(pq_u, 0, 640 * sizeof(float), stream);   // pq+ph+pc contiguous
    for (int stp = 0; stp < 2; ++stp) {
        pool_lstm_kernel<<<1, 640, 0, stream>>>(gsWih, gsWhh, gsbih, gsbhh, pq_u, ph_u, pc_u);
        pool_scores_kernel<<<32, 256, 0, stream>>>(uafT, q_u, ph_u, scores, pmax);
        pool_softmax_kernel<<<1, 256, 0, stream>>>(scores, pmax, pden);
        pool_r_kernel<<<160, 256, 0, stream>>>(uafT, q_u, scores, pden, pq_u);
    }
    hipMemsetAsync(pq_v, 0, 640 * sizeof(float), stream);
    for (int stp = 0; stp < 2; ++stp) {
        pool_lstm_kernel<<<1, 640, 0, stream>>>(gvWih, gvWhh, gvbih, gvbhh, pq_v, ph_v, pc_v);
        pool_scores_kernel<<<32, 256, 0, stream>>>(vafT, q_v, ph_v, scores, pmax);
        pool_softmax_kernel<<<1, 256, 0, stream>>>(scores, pmax, pden);
        pool_r_kernel<<<160, 256, 0, stream>>>(vafT, q_v, scores, pden, pq_v);
    }

    // ---- final MLP ----
    mlp_kernel<<<1, 512, 0, stream>>>(pq_u, pq_v, w1, b1, w2, b2, w3, b3, w4, b4, out);
}

// Round 3
// 1142.144 us; speedup vs baseline: 2.5114x; 1.9520x over previous
//
#include <hip/hip_runtime.h>
#include <cstdint>
#include <cstddef>

#define NN 8000
#define NE 128000
#define NDv 40
#define EDv 10

typedef __attribute__((ext_vector_type(8))) short short8v;
typedef __attribute__((ext_vector_type(4))) float f32x4;

__device__ __forceinline__ float rcp_fast(float x) { return __builtin_amdgcn_rcpf(x); }
__device__ __forceinline__ float sigm(float x) { return rcp_fast(1.f + __expf(-x)); }
__device__ __forceinline__ float ftanh(float x) {
    float e = __expf(2.f * x);
    return 1.f - 2.f * rcp_fast(e + 1.f);
}
__device__ __forceinline__ short f2bf(float x) {   // RNE f32 -> bf16
    unsigned u = __builtin_bit_cast(unsigned, x);
    u += 0x7fffu + ((u >> 16) & 1u);
    return (short)(u >> 16);
}
__device__ __forceinline__ float wsum(float v) {
    for (int o = 32; o; o >>= 1) v += __shfl_down(v, o);
    return v;
}
__device__ __forceinline__ float wmax(float v) {
    for (int o = 32; o; o >>= 1) v = fmaxf(v, __shfl_down(v, o));
    return v;
}

// ---------------- CSR build (per graph, edge index is static) ----------------

__global__ __launch_bounds__(256) void csr_deg_kernel(const int* __restrict__ ei, int* __restrict__ deg) {
    int e = blockIdx.x * 256 + threadIdx.x;
    if (e < NE) atomicAdd(&deg[ei[e]], 1);
}

// single wave: lane l scans nodes [l*125, (l+1)*125)
__global__ __launch_bounds__(64) void csr_scan_kernel(const int* __restrict__ deg, int* __restrict__ off,
                                                      int* __restrict__ woff) {
    int l = threadIdx.x;
    int base = l * 125;
    int s = 0;
    for (int i = 0; i < 125; ++i) s += deg[base + i];
    int pre = s;
    for (int o = 1; o < 64; o <<= 1) { int t = __shfl_up(pre, o); if (l >= o) pre += t; }
    pre -= s;   // exclusive prefix
    int run = pre;
    for (int i = 0; i < 125; ++i) {
        off[base + i] = run; woff[base + i] = run;
        run += deg[base + i];
    }
    if (l == 63) off[NN] = run;
}

__global__ __launch_bounds__(256) void csr_fill_kernel(const int* __restrict__ ei, int* __restrict__ woff,
                                                       int* __restrict__ elist) {
    int e = blockIdx.x * 256 + threadIdx.x;
    if (e < NE) { int p = atomicAdd(&woff[ei[e]], 1); elist[p] = e; }
}

// ---------------- message passing ----------------

__global__ __launch_bounds__(256) void node_proj_kernel(const float* __restrict__ h, const float* __restrict__ Uw,
                                                        float* __restrict__ A, float* __restrict__ B) {
    int t = blockIdx.x * 256 + threadIdx.x;   // exactly 8000*40
    int n = t / NDv, i = t % NDv;
    const float* wa = Uw + i * 90;
    const float* hr = h + n * NDv;
    float a = 0.f, b = 0.f;
#pragma unroll
    for (int k = 0; k < NDv; ++k) { float hv = hr[k]; a += wa[k] * hv; b += wa[40 + k] * hv; }
    A[t] = a; B[t] = b;
}

// msg[n,i] = deg(n)*(A[n,i]+Ub[i]) + sum_{e: src=n} ( B[dst_e,i] + Uw[i,80:90]·ef[e] )
__global__ __launch_bounds__(256) void msg_gather_kernel(const int* __restrict__ off, const int* __restrict__ elist,
                                                         const int* __restrict__ ei, const float* __restrict__ ef,
                                                         const float* __restrict__ Uw, const float* __restrict__ Ub,
                                                         const float* __restrict__ A, const float* __restrict__ B,
                                                         float* __restrict__ msg) {
    int t = blockIdx.x * 256 + threadIdx.x;   // exactly 8000*40
    int n = t / NDv, i = t % NDv;
    float w[10];
    const float* we = Uw + i * 90 + 80;
#pragma unroll
    for (int k = 0; k < EDv; ++k) w[k] = we[k];
    int p0 = off[n], p1 = off[n + 1];
    float acc = (float)(p1 - p0) * (A[t] + Ub[i]);
    for (int p = p0; p < p1; ++p) {
        int e = elist[p];
        int d = ei[NE + e];
        const float* efr = ef + e * EDv;
        float s = B[d * NDv + i];
#pragma unroll
        for (int k = 0; k < EDv; ++k) s += w[k] * efr[k];
        acc += s;
    }
    msg[t] = acc;
}

__global__ __launch_bounds__(256) void node_update_kernel(const float* __restrict__ h, const float* __restrict__ msg,
                                                          const float* __restrict__ Mw, const float* __restrict__ Mb,
                                                          float* __restrict__ hout) {
    int t = blockIdx.x * 256 + threadIdx.x;   // exactly 8000*40
    int n = t / NDv, i = t % NDv;
    const float* w = Mw + i * 80;
    const float* hr = h + n * NDv;
    const float* mr = msg + n * NDv;
    float acc = Mb[i];
#pragma unroll
    for (int k = 0; k < NDv; ++k) acc += w[k] * hr[k];
#pragma unroll
    for (int k = 0; k < NDv; ++k) acc += w[40 + k] * mr[k];
    hout[t] = fmaxf(acc, 0.f);
}

// ---------------- set2set (pair, per-node LSTM h_d=40) ----------------

__global__ __launch_bounds__(256) void s2s_gates_kernel(const float* __restrict__ q, const float* __restrict__ hh,
                                                        const float* __restrict__ Wih, const float* __restrict__ Whh,
                                                        const float* __restrict__ bih, const float* __restrict__ bhh,
                                                        float* __restrict__ gatesT) {
    int t = blockIdx.x * 256 + threadIdx.x;   // exactly 8000*20
    int n = t % NN;
    int jg = t / NN;
    float qr[80];
#pragma unroll
    for (int k4 = 0; k4 < 20; ++k4) {
        float4 v = *reinterpret_cast<const float4*>(q + n * 80 + k4 * 4);
        qr[k4 * 4 + 0] = v.x; qr[k4 * 4 + 1] = v.y; qr[k4 * 4 + 2] = v.z; qr[k4 * 4 + 3] = v.w;
    }
    float hr[40];
#pragma unroll
    for (int k4 = 0; k4 < 10; ++k4) {
        float4 v = *reinterpret_cast<const float4*>(hh + n * 40 + k4 * 4);
        hr[k4 * 4 + 0] = v.x; hr[k4 * 4 + 1] = v.y; hr[k4 * 4 + 2] = v.z; hr[k4 * 4 + 3] = v.w;
    }
#pragma unroll
    for (int jj = 0; jj < 8; ++jj) {
        int j = jg * 8 + jj;
        const float* wi = Wih + j * 80;
        const float* wh = Whh + j * 40;
        float acc = bih[j] + bhh[j];
#pragma unroll
        for (int k = 0; k < 80; ++k) acc += wi[k] * qr[k];
#pragma unroll
        for (int k = 0; k < 40; ++k) acc += wh[k] * hr[k];
        gatesT[j * NN + n] = acc;
    }
}

__global__ __launch_bounds__(256) void s2s_update_kernel(const float* __restrict__ gatesT,
                                                         const float* __restrict__ h0, const float* __restrict__ ht,
                                                         float* __restrict__ hh, float* __restrict__ cc,
                                                         float* __restrict__ q) {
    int n = blockIdx.x * 256 + threadIdx.x;
    if (n >= NN) return;
    float hreg[40];
    float e0 = 0.f, e1 = 0.f;
#pragma unroll
    for (int i = 0; i < 40; ++i) {
        float gi = gatesT[i * NN + n];
        float gf = gatesT[(40 + i) * NN + n];
        float gg = gatesT[(80 + i) * NN + n];
        float go = gatesT[(120 + i) * NN + n];
        float cn = sigm(gf) * cc[n * 40 + i] + sigm(gi) * ftanh(gg);
        cc[n * 40 + i] = cn;
        float hn = sigm(go) * ftanh(cn);
        hreg[i] = hn;
        e0 += h0[n * 40 + i] * hn;
        e1 += ht[n * 40 + i] * hn;
    }
    float m = fmaxf(e0, e1);
    float p0 = __expf(e0 - m), p1 = __expf(e1 - m);
    float inv = rcp_fast(p0 + p1);
    float a0 = p0 * inv, a1 = p1 * inv;
#pragma unroll
    for (int i = 0; i < 40; ++i) {
        hh[n * 40 + i] = hreg[i];
        q[n * 80 + i] = hreg[i];
        q[n * 80 + 40 + i] = a0 * h0[n * 40 + i] + a1 * ht[n * 40 + i];
    }
}

// ---------------- bf16 casts ----------------

__global__ __launch_bounds__(256) void cast_pad_kernel(const float* __restrict__ g, short* __restrict__ o) {
    int t = blockIdx.x * 256 + threadIdx.x;   // exactly 8000*96
    int m = t / 96, k = t % 96;
    o[t] = (k < 80) ? f2bf(g[m * 80 + k]) : (short)0;
}

__global__ __launch_bounds__(256) void cast_t_kernel(const float* __restrict__ g, short* __restrict__ o) {
    int t = blockIdx.x * 256 + threadIdx.x;   // exactly 80*8000
    int m = t % NN, f = t / NN;
    o[t] = f2bf(g[m * 80 + f]);
}

// ---------------- interaction: I = gu @ gv^T via MFMA ----------------

__global__ __launch_bounds__(256) void inter_mfma_kernel(const short* __restrict__ gub, const short* __restrict__ gvb,
                                                         float* __restrict__ out) {
    int tid = threadIdx.x;
    int w = tid >> 6, l = tid & 63;
    int lrow = l & 15, lk = l >> 4;
    int m0 = blockIdx.y * 64, n0 = blockIdx.x * 64;
    const short* arow = gub + (size_t)(m0 + w * 16 + lrow) * 96 + lk * 8;
    f32x4 acc[4] = {};
#pragma unroll
    for (int ks = 0; ks < 3; ++ks) {
        short8v a = *reinterpret_cast<const short8v*>(arow + ks * 32);
#pragma unroll
        for (int nt = 0; nt < 4; ++nt) {
            short8v b = *reinterpret_cast<const short8v*>(gvb + (size_t)(n0 + nt * 16 + lrow) * 96 + ks * 32 + lk * 8);
            acc[nt] = __builtin_amdgcn_mfma_f32_16x16x32_bf16(a, b, acc[nt], 0, 0, 0);
        }
    }
#pragma unroll
    for (int nt = 0; nt < 4; ++nt)
#pragma unroll
        for (int r = 0; r < 4; ++r)
            out[(size_t)(m0 + w * 16 + lk * 4 + r) * NN + (n0 + nt * 16 + lrow)] = acc[nt][r];
}

// ---------------- u_afterT[f][m] = sum_n tanh(I[m][n]) * gv[n][f] ----------------

__global__ __launch_bounds__(256) void after_u_kernel(const float* __restrict__ I, const short* __restrict__ gvT,
                                                      float* __restrict__ uafT) {
    int tid = threadIdx.x;
    int w = tid >> 6, l = tid & 63;
    int lrow = l & 15, lk = l >> 4;
    int m = blockIdx.x * 64 + w * 16 + lrow;
    int nbase = blockIdx.y * 1600;
    f32x4 acc[5] = {};
    for (int nc = 0; nc < 50; ++nc) {
        int n = nbase + nc * 32 + lk * 8;
        const float* ip = I + (size_t)m * NN + n;
        short8v a;
#pragma unroll
        for (int j = 0; j < 8; ++j) a[j] = f2bf(ftanh(ip[j]));
#pragma unroll
        for (int ft = 0; ft < 5; ++ft) {
            short8v b = *reinterpret_cast<const short8v*>(gvT + (ft * 16 + lrow) * NN + n);
            acc[ft] = __builtin_amdgcn_mfma_f32_16x16x32_bf16(a, b, acc[ft], 0, 0, 0);
        }
    }
    int mout = blockIdx.x * 64 + w * 16 + lk * 4;
#pragma unroll
    for (int ft = 0; ft < 5; ++ft)
#pragma unroll
        for (int r = 0; r < 4; ++r)
            atomicAdd(&uafT[(ft * 16 + lrow) * NN + mout + r], acc[ft][r]);
}

// ---------------- v_afterT[f][n] = sum_m gu[m][f] * tanh(I[m][n]) ----------------

__global__ __launch_bounds__(256) void after_v_kernel(const float* __restrict__ I, const short* __restrict__ guT,
                                                      float* __restrict__ vafT) {
    __shared__ short PT[64][40];
    int tid = threadIdx.x;
    int w = tid >> 6, l = tid & 63;
    int lcol = l & 15, lk = l >> 4;
    int n0 = blockIdx.x * 64;
    int mbase = blockIdx.y * 1600;
    int lr = tid & 31;
    int lc = (tid >> 5) * 8;
    f32x4 acc[5] = {};
    for (int mc = 0; mc < 50; ++mc) {
        int mrow = mbase + mc * 32 + lr;
        const float* ip = I + (size_t)mrow * NN + n0 + lc;
        float v[8];
#pragma unroll
        for (int j = 0; j < 8; ++j) v[j] = ftanh(ip[j]);
        __syncthreads();
#pragma unroll
        for (int j = 0; j < 8; ++j) PT[lc + j][lr] = f2bf(v[j]);
        __syncthreads();
        short8v b = *reinterpret_cast<const short8v*>(&PT[w * 16 + lcol][lk * 8]);
#pragma unroll
        for (int ft = 0; ft < 5; ++ft) {
            short8v a = *reinterpret_cast<const short8v*>(guT + (ft * 16 + lcol) * NN + mbase + mc * 32 + lk * 8);
            acc[ft] = __builtin_amdgcn_mfma_f32_16x16x32_bf16(a, b, acc[ft], 0, 0, 0);
        }
    }
    int ncol = n0 + w * 16 + lcol;
#pragma unroll
    for (int ft = 0; ft < 5; ++ft)
#pragma unroll
        for (int r = 0; r < 4; ++r)
            atomicAdd(&vafT[(ft * 16 + lk * 4 + r) * NN + ncol], acc[ft][r]);
}

// ---------------- set2set pool (batch 1, h_d=160) — parallel gates + pointwise ----------------

// one wave per gate row j (640 rows)
__global__ __launch_bounds__(64) void gates_pool_kernel(const float* __restrict__ Wih, const float* __restrict__ Whh,
                                                        const float* __restrict__ bih, const float* __restrict__ bhh,
                                                        const float* __restrict__ q, const float* __restrict__ h,
                                                        float* __restrict__ gts) {
    int j = blockIdx.x;
    int lane = threadIdx.x;
    const float* wi = Wih + j * 320;
    const float* wh = Whh + j * 160;
    float p = 0.f;
#pragma unroll
    for (int k4 = 0; k4 < 5; ++k4) { int k = lane + k4 * 64; p += wi[k] * q[k]; }
#pragma unroll
    for (int k4 = 0; k4 < 3; ++k4) { int k = lane + k4 * 64; if (k < 160) p += wh[k] * h[k]; }
    p = wsum(p);
    if (lane == 0) gts[j] = p + bih[j] + bhh[j];
}

__global__ __launch_bounds__(256) void pool_point_kernel(const float* __restrict__ gts, float* __restrict__ h,
                                                         float* __restrict__ c, float* __restrict__ q) {
    int tid = threadIdx.x;
    if (tid < 160) {
        float cn = sigm(gts[160 + tid]) * c[tid] + sigm(gts[tid]) * ftanh(gts[320 + tid]);
        c[tid] = cn;
        float hn = sigm(gts[480 + tid]) * ftanh(cn);
        h[tid] = hn;
        q[tid] = hn;   // q_star[0:160] = h
    }
}

__global__ __launch_bounds__(256) void pool_scores_kernel(const float* __restrict__ afT, const float* __restrict__ g,
                                                          const float* __restrict__ h, float* __restrict__ scores,
                                                          float* __restrict__ pmax) {
    int tid = threadIdx.x;
    int n = blockIdx.x * 256 + tid;
    float s = -3.4e38f;
    if (n < NN) {
        float acc = 0.f;
#pragma unroll 8
        for (int k = 0; k < 80; ++k) acc += afT[k * NN + n] * h[k];
        const float* gr = g + n * 80;
#pragma unroll 8
        for (int k = 0; k < 80; ++k) acc += gr[k] * h[80 + k];
        scores[n] = acc;
        s = acc;
    }
    __shared__ float red[4];
    float m = wmax(s);
    if ((tid & 63) == 0) red[tid >> 6] = m;
    __syncthreads();
    if (tid == 0) pmax[blockIdx.x] = fmaxf(fmaxf(red[0], red[1]), fmaxf(red[2], red[3]));
}

__global__ __launch_bounds__(256) void pool_softmax_kernel(float* __restrict__ scores, const float* __restrict__ pmax,
                                                           float* __restrict__ denom) {
    int tid = threadIdx.x;
    __shared__ float sm;
    __shared__ float red[4];
    float m = (tid < 32) ? pmax[tid] : -3.4e38f;
    m = wmax(m);
    if (tid == 0) sm = m;
    __syncthreads();
    float mm = sm;
    float lsum = 0.f;
    for (int n = tid; n < NN; n += 256) {
        float e = __expf(scores[n] - mm);
        scores[n] = e;
        lsum += e;
    }
    float w = wsum(lsum);
    if ((tid & 63) == 0) red[tid >> 6] = w;
    __syncthreads();
    if (tid == 0) denom[0] = red[0] + red[1] + red[2] + red[3];
}

__global__ __launch_bounds__(256) void pool_r_kernel(const float* __restrict__ afT, const float* __restrict__ g,
                                                     const float* __restrict__ scores, const float* __restrict__ denom,
                                                     float* __restrict__ q) {
    int f = blockIdx.x;   // 0..159
    int tid = threadIdx.x;
    float acc = 0.f;
    if (f < 80) {
        const float* x = afT + (size_t)f * NN;
        for (int n = tid; n < NN; n += 256) acc += scores[n] * x[n];
    } else {
        const float* x = g + (f - 80);
        for (int n = tid; n < NN; n += 256) acc += scores[n] * x[(size_t)n * 80];
    }
    float w = wsum(acc);
    __shared__ float red[4];
    if ((tid & 63) == 0) red[tid >> 6] = w;
    __syncthreads();
    if (tid == 0) q[160 + f] = (red[0] + red[1] + red[2] + red[3]) * rcp_fast(denom[0]);
}

// ---------------- final MLP (parallel per-row GEMVs) ----------------

__global__ __launch_bounds__(640) void concat_kernel(const float* __restrict__ cu, const float* __restrict__ cv,
                                                     float* __restrict__ x0) {
    int tid = threadIdx.x;
    x0[tid] = (tid < 320) ? cu[tid] : cv[tid - 320];
}

// y[j] = act(W[j,:K]·x + b[j]); grid = rows, one wave
__global__ __launch_bounds__(64) void gemv_kernel(const float* __restrict__ W, const float* __restrict__ b,
                                                  const float* __restrict__ x, float* __restrict__ y,
                                                  int K, int relu) {
    int j = blockIdx.x;
    int lane = threadIdx.x;
    const float* w = W + (size_t)j * K;
    float p = 0.f;
    for (int k = lane; k < K; k += 64) p += w[k] * x[k];
    p = wsum(p);
    if (lane == 0) {
        p += b[j];
        y[j] = relu ? fmaxf(p, 0.f) : p;
    }
}

// ---------------- launch ----------------

extern "C" void kernel_launch(void* const* d_in, const int* in_sizes, int n_in,
                              void* d_out, int out_size, void* d_ws, size_t ws_size,
                              hipStream_t stream) {
    const float* nodes_u = (const float*)d_in[0];
    const int* ei_u = (const int*)d_in[1];
    const float* ef_u = (const float*)d_in[2];
    const float* nodes_v = (const float*)d_in[3];
    const int* ei_v = (const int*)d_in[4];
    const float* ef_v = (const float*)d_in[5];
    const float* Uw_u = (const float*)d_in[6];
    const float* Ub_u = (const float*)d_in[7];
    const float* Mw_u = (const float*)d_in[8];
    const float* Mb_u = (const float*)d_in[9];
    const float* Uw_v = (const float*)d_in[10];
    const float* Ub_v = (const float*)d_in[11];
    const float* Mw_v = (const float*)d_in[12];
    const float* Mb_v = (const float*)d_in[13];
    const float* lsWih = (const float*)d_in[14];
    const float* lsWhh = (const float*)d_in[15];
    const float* lsbih = (const float*)d_in[16];
    const float* lsbhh = (const float*)d_in[17];
    const float* lvWih = (const float*)d_in[18];
    const float* lvWhh = (const float*)d_in[19];
    const float* lvbih = (const float*)d_in[20];
    const float* lvbhh = (const float*)d_in[21];
    const float* gsWih = (const float*)d_in[22];
    const float* gsWhh = (const float*)d_in[23];
    const float* gsbih = (const float*)d_in[24];
    const float* gsbhh = (const float*)d_in[25];
    const float* gvWih = (const float*)d_in[26];
    const float* gvWhh = (const float*)d_in[27];
    const float* gvbih = (const float*)d_in[28];
    const float* gvbhh = (const float*)d_in[29];
    const float* w1 = (const float*)d_in[30];
    const float* b1 = (const float*)d_in[31];
    const float* w2 = (const float*)d_in[32];
    const float* b2 = (const float*)d_in[33];
    const float* w3 = (const float*)d_in[34];
    const float* b3 = (const float*)d_in[35];
    const float* w4 = (const float*)d_in[36];
    const float* b4 = (const float*)d_in[37];

    float* ws = (float*)d_ws;
    float* hA_u = ws + 0;
    float* hB_u = ws + 320000;
    float* hA_v = ws + 640000;
    float* hB_v = ws + 960000;
    float* msg  = ws + 1280000;
    float* Apro = ws + 1600000;
    float* Bpro = ws + 1920000;
    float* q_u  = ws + 2240000;   // gu [8000,80]
    float* q_v  = ws + 2880000;   // gv [8000,80]
    float* hh   = ws + 3520000;
    float* cc   = ws + 3840000;
    float* gT   = ws + 4160000;   // gates transposed [160][8000]
    float* uafT = ws + 5440000;   // [80][8000]
    float* vafT = ws + 6080000;   // [80][8000]
    float* scores = ws + 6720000;
    float* pmax = ws + 6728000;
    float* pden = ws + 6728032;
    float* pq_u = ws + 6728040;
    float* ph_u = ws + 6728360;
    float* pc_u = ws + 6728520;
    float* pq_v = ws + 6728680;
    float* ph_v = ws + 6729000;
    float* pc_v = ws + 6729160;
    float* pgts = ws + 6729320;   // 640
    float* mx0  = ws + 6729960;   // 640
    float* mx1  = ws + 6730600;   // 360
    float* mx2  = ws + 6730960;   // 200
    float* mx3  = ws + 6731160;   // 120
    int* ioff_u   = (int*)(ws + 6731280);   // 8001 (pad 8064)
    int* ielist_u = (int*)(ws + 6739344);   // 128000
    int* ioff_v   = (int*)(ws + 6867344);   // 8064
    int* ielist_v = (int*)(ws + 6875408);   // 128000
    int* iwoff    = (int*)(ws + 7003408);   // 8064
    int* ideg     = (int*)(ws + 7011472);   // 8064

    // bf16 buffers reuse the (dead by then) message-passing region
    short* guT = (short*)(ws + 0);        // [80][8000]
    short* gvT = (short*)(ws + 320000);   // [80][8000]
    short* gub = (short*)(ws + 640000);   // [8000][96]
    short* gvb = (short*)(ws + 1024000);  // [8000][96]

    float* out = (float*)d_out;
    float* inter = out + 1;

    // ---- CSR build: u ----
    hipMemsetAsync(ideg, 0, NN * sizeof(int), stream);
    csr_deg_kernel<<<500, 256, 0, stream>>>(ei_u, ideg);
    csr_scan_kernel<<<1, 64, 0, stream>>>(ideg, ioff_u, iwoff);
    csr_fill_kernel<<<500, 256, 0, stream>>>(ei_u, iwoff, ielist_u);
    // ---- CSR build: v ----
    hipMemsetAsync(ideg, 0, NN * sizeof(int), stream);
    csr_deg_kernel<<<500, 256, 0, stream>>>(ei_v, ideg);
    csr_scan_kernel<<<1, 64, 0, stream>>>(ideg, ioff_v, iwoff);
    csr_fill_kernel<<<500, 256, 0, stream>>>(ei_v, iwoff, ielist_v);

    // ---- message passing: u ----
    {
        const float* cur = nodes_u;
        float* nxt[3] = {hA_u, hB_u, hA_u};
        for (int k = 0; k < 3; ++k) {
            node_proj_kernel<<<1250, 256, 0, stream>>>(cur, Uw_u + k * 3600, Apro, Bpro);
            msg_gather_kernel<<<1250, 256, 0, stream>>>(ioff_u, ielist_u, ei_u, ef_u, Uw_u + k * 3600,
                                                        Ub_u + k * 40, Apro, Bpro, msg);
            node_update_kernel<<<1250, 256, 0, stream>>>(cur, msg, Mw_u + k * 3200, Mb_u + k * 40, nxt[k]);
            cur = nxt[k];
        }
    }
    // ---- message passing: v ----
    {
        const float* cur = nodes_v;
        float* nxt[3] = {hA_v, hB_v, hA_v};
        for (int k = 0; k < 3; ++k) {
            node_proj_kernel<<<1250, 256, 0, stream>>>(cur, Uw_v + k * 3600, Apro, Bpro);
            msg_gather_kernel<<<1250, 256, 0, stream>>>(ioff_v, ielist_v, ei_v, ef_v, Uw_v + k * 3600,
                                                        Ub_v + k * 40, Apro, Bpro, msg);
            node_update_kernel<<<1250, 256, 0, stream>>>(cur, msg, Mw_v + k * 3200, Mb_v + k * 40, nxt[k]);
            cur = nxt[k];
        }
    }

    // ---- set2set pair ----
    hipMemsetAsync(q_u, 0, 640000 * sizeof(float), stream);
    hipMemsetAsync(hh, 0, 640000 * sizeof(float), stream);   // hh + cc contiguous
    for (int stp = 0; stp < 2; ++stp) {
        s2s_gates_kernel<<<625, 256, 0, stream>>>(q_u, hh, lsWih, lsWhh, lsbih, lsbhh, gT);
        s2s_update_kernel<<<32, 256, 0, stream>>>(gT, nodes_u, hA_u, hh, cc, q_u);
    }
    hipMemsetAsync(q_v, 0, 640000 * sizeof(float), stream);
    hipMemsetAsync(hh, 0, 640000 * sizeof(float), stream);
    for (int stp = 0; stp < 2; ++stp) {
        s2s_gates_kernel<<<625, 256, 0, stream>>>(q_v, hh, lvWih, lvWhh, lvbih, lvbhh, gT);
        s2s_update_kernel<<<32, 256, 0, stream>>>(gT, nodes_v, hA_v, hh, cc, q_v);
    }

    // ---- bf16 casts ----
    cast_t_kernel<<<2500, 256, 0, stream>>>(q_u, guT);
    cast_t_kernel<<<2500, 256, 0, stream>>>(q_v, gvT);
    cast_pad_kernel<<<3000, 256, 0, stream>>>(q_u, gub);
    cast_pad_kernel<<<3000, 256, 0, stream>>>(q_v, gvb);

    // ---- interaction + after-features (MFMA) ----
    inter_mfma_kernel<<<dim3(125, 125), 256, 0, stream>>>(gub, gvb, inter);
    hipMemsetAsync(uafT, 0, 1280000 * sizeof(float), stream);   // uafT + vafT contiguous
    after_u_kernel<<<dim3(125, 5), 256, 0, stream>>>(inter, gvT, uafT);
    after_v_kernel<<<dim3(125, 5), 256, 0, stream>>>(inter, guT, vafT);

    // ---- pools ----
    hipMemsetAsync(pq_u, 0, 640 * sizeof(float), stream);   // pq+ph+pc contiguous
    for (int stp = 0; stp < 2; ++stp) {
        gates_pool_kernel<<<640, 64, 0, stream>>>(gsWih, gsWhh, gsbih, gsbhh, pq_u, ph_u, pgts);
        pool_point_kernel<<<1, 256, 0, stream>>>(pgts, ph_u, pc_u, pq_u);
        pool_scores_kernel<<<32, 256, 0, stream>>>(uafT, q_u, ph_u, scores, pmax);
        pool_softmax_kernel<<<1, 256, 0, stream>>>(scores, pmax, pden);
        pool_r_kernel<<<160, 256, 0, stream>>>(uafT, q_u, scores, pden, pq_u);
    }
    hipMemsetAsync(pq_v, 0, 640 * sizeof(float), stream);
    for (int stp = 0; stp < 2; ++stp) {
        gates_pool_kernel<<<640, 64, 0, stream>>>(gvWih, gvWhh, gvbih, gvbhh, pq_v, ph_v, pgts);
        pool_point_kernel<<<1, 256, 0, stream>>>(pgts, ph_v, pc_v, pq_v);
        pool_scores_kernel<<<32, 256, 0, stream>>>(vafT, q_v, ph_v, scores, pmax);
        pool_softmax_kernel<<<1, 256, 0, stream>>>(scores, pmax, pden);
        pool_r_kernel<<<160, 256, 0, stream>>>(vafT, q_v, scores, pden, pq_v);
    }

    // ---- final MLP ----
    concat_kernel<<<1, 640, 0, stream>>>(pq_u, pq_v, mx0);
    gemv_kernel<<<360, 64, 0, stream>>>(w1, b1, mx0, mx1, 640, 1);
    gemv_kernel<<<200, 64, 0, stream>>>(w2, b2, mx1, mx2, 360, 1);
    gemv_kernel<<<120, 64, 0, stream>>>(w3, b3, mx2, mx3, 200, 1);
    gemv_kernel<<<1, 64, 0, stream>>>(w4, b4, mx3, out, 120, 0);
}